// Round 1
// 538.460 us; speedup vs baseline: 1.2032x; 1.2032x over previous
//
#include <hip/hip_runtime.h>
#include <stdint.h>

typedef __bf16 bf16;
typedef __bf16 bf16x4 __attribute__((ext_vector_type(4)));
typedef __bf16 bf16x8 __attribute__((ext_vector_type(8)));
typedef float f32x4 __attribute__((ext_vector_type(4)));

using gp_t = __attribute__((address_space(1))) const void*;
using lp_t = __attribute__((address_space(3))) void*;

__device__ __forceinline__ void gld16(const void* g, void* l) {
  __builtin_amdgcn_global_load_lds((gp_t)g, (lp_t)l, 16, 0, 0);
}

// ---------------------------------------------------------------------------
// fp32 -> bf16 conversion, segment table (one kernel, grid-stride per segment)
// ---------------------------------------------------------------------------
struct CvtSegs {
  const float* src[10];
  bf16* dst[10];
  int cnt[10];     // element counts, divisible by 4
  int n;
};

__global__ void cvt_kernel(CvtSegs segs) {
  const int stride = gridDim.x * blockDim.x;
  const int t0 = blockIdx.x * blockDim.x + threadIdx.x;
  for (int s = 0; s < segs.n; s++) {
    const float4* src = (const float4*)segs.src[s];
    bf16x4* dst = (bf16x4*)segs.dst[s];
    int cnt4 = segs.cnt[s] >> 2;
    for (int idx = t0; idx < cnt4; idx += stride) {
      float4 v = src[idx];
      bf16x4 o; o[0] = (bf16)v.x; o[1] = (bf16)v.y; o[2] = (bf16)v.z; o[3] = (bf16)v.w;
      dst[idx] = o;
    }
  }
}

// ---------------------------------------------------------------------------
// C[M,N] = A[M,K] @ W[N,K]^T + bias[N]   (bf16 A via global_load_lds;
// W bf16 fast path or fp32 float4+cvt fallback).  128x128 tile, BK=64,
// XOR-swizzled LDS, m97-style 2-barrier K-loop.
// store_sel: 0 = bf16 row-major C
//            2 = fp32 row-major C (final output)
//            3 = fused KV: col<128 -> K row-major (b,s,d) at C;
//                          col>=128 -> V^T (b,d,s) at C + 1048576 elements
// ---------------------------------------------------------------------------
__global__ __launch_bounds__(256, 2)
void gemm_bt(const bf16* __restrict__ A, const void* __restrict__ Wv,
             const void* __restrict__ biasv, void* __restrict__ Cv,
             int M, int N, int K, int w_fp32, int bias_fp32, int store_sel)
{
  __shared__ __align__(16) bf16 As[128 * 64];
  __shared__ __align__(16) bf16 Bs[128 * 64];
  const int tid  = threadIdx.x;
  const int lane = tid & 63;
  const int w    = tid >> 6;
  const int wm   = w >> 1, wn = w & 1;
  const int quad = lane >> 4, l16 = lane & 15;
  const int m0 = blockIdx.x * 128, n0 = blockIdx.y * 128;

  f32x4 acc[4][4] = {};

  for (int k0 = 0; k0 < K; k0 += 64) {
#pragma unroll
    for (int it = 0; it < 4; it++) {
      int c = tid + it * 256;          // lane-contiguous LDS slots (required)
      int row = c >> 3;
      int cc  = (c & 7) ^ (row & 7);   // XOR swizzle on 16B chunks
      gld16(A + (size_t)(m0 + row) * K + k0 + cc * 8, &As[c * 8]);
      size_t woff = (size_t)(n0 + row) * K + k0 + cc * 8;
      if (!w_fp32) {
        gld16((const bf16*)Wv + woff, &Bs[c * 8]);
      } else {
        const float* Wf = (const float*)Wv;
        float4 x0 = *(const float4*)(Wf + woff);
        float4 x1 = *(const float4*)(Wf + woff + 4);
        bf16x8 v;
        v[0] = (bf16)x0.x; v[1] = (bf16)x0.y; v[2] = (bf16)x0.z; v[3] = (bf16)x0.w;
        v[4] = (bf16)x1.x; v[5] = (bf16)x1.y; v[6] = (bf16)x1.z; v[7] = (bf16)x1.w;
        *(bf16x8*)&Bs[c * 8] = v;
      }
    }
    __syncthreads();                   // drains vmcnt (gld16) + lgkmcnt
#pragma unroll
    for (int dk = 0; dk < 2; dk++) {
      bf16x8 af[4], bw[4];
#pragma unroll
      for (int i = 0; i < 4; i++) {
        int row = wm * 64 + i * 16 + l16;
        af[i] = *(const bf16x8*)&As[(row * 8 + ((dk * 4 + quad) ^ (row & 7))) * 8];
      }
#pragma unroll
      for (int j = 0; j < 4; j++) {
        int row = wn * 64 + j * 16 + l16;
        bw[j] = *(const bf16x8*)&Bs[(row * 8 + ((dk * 4 + quad) ^ (row & 7))) * 8];
      }
#pragma unroll
      for (int i = 0; i < 4; i++)
#pragma unroll
        for (int j = 0; j < 4; j++)
          acc[i][j] = __builtin_amdgcn_mfma_f32_16x16x32_bf16(af[i], bw[j], acc[i][j], 0, 0, 0);
    }
    __syncthreads();
  }

  // epilogue: C/D layout col=lane&15, row=quad*4+reg (m89/m91-verified)
#pragma unroll
  for (int j = 0; j < 4; j++) {
    int col = n0 + wn * 64 + j * 16 + l16;
    float bv = bias_fp32 ? ((const float*)biasv)[col] : (float)((const bf16*)biasv)[col];
#pragma unroll
    for (int i = 0; i < 4; i++) {
#pragma unroll
      for (int r = 0; r < 4; r++) {
        int row = m0 + wm * 64 + i * 16 + quad * 4 + r;
        float v = acc[i][j][r] + bv;
        if (store_sel == 0) {
          ((bf16*)Cv)[(size_t)row * N + col] = (bf16)v;
        } else if (store_sel == 2) {
          ((float*)Cv)[(size_t)row * N + col] = v;
        } else {   // fused KV split
          int b = row >> 11, s = row & 2047;   // S=2048 per batch
          if (col < 128) {
            ((bf16*)Cv)[(size_t)row * 128 + col] = (bf16)v;              // K (b,s,d)
          } else {
            ((bf16*)Cv + 1048576)[((size_t)(b * 128 + (col - 128))) * 2048 + s] = (bf16)v; // V^T
          }
        }
      }
    }
  }
}

// ---------------------------------------------------------------------------
// Causal MQA flash attention, wave-private softmax.
// grid = (p=8, bh=64), block = 256 (4 waves).
// LOAD BALANCE: block p processes TWO Q-tiles, qi = p and qi = 15-p.
// Per-block work = (2p+2) + (2(15-p)+2) = 36 k-tile iterations — constant
// across the whole grid, killing the causal tail (previous version: 2..32
// tiles per block -> 12% occupancy, half the CUs idle in the tail).
// 512 blocks = exactly 2 resident blocks/CU (LDS 48KB allows 3).
// BQ=128: wave w owns q-rows w*32..w*32+31 and the FULL 64-key tile ->
// softmax is wave-local (register m/l state, in-wave shuffles, private P).
// Barriers: 2 per k-tile (after cooperative K/V stage; before restage).
// AO may ALIAS Qg in place: each block reads/writes only the Q regions of
// the two tiles it owns; tile B's Q is read before tile B's output store.
// LDS: Ks 16 KB + Vs 16 KB + Ps 4x(32x64) 16 KB = 48 KB.
// ---------------------------------------------------------------------------
__global__ __launch_bounds__(256, 2)
void mqa_attn(const bf16* Qg, const bf16* __restrict__ Kg,
              const bf16* __restrict__ Vtg, bf16* AO)
{
  __shared__ __align__(16) bf16 Ks[64 * 128];
  __shared__ __align__(16) bf16 Vs[128 * 64];
  __shared__ __align__(16) bf16 Ps[4 * 32 * 64];

  const int tid  = threadIdx.x;
  const int lane = tid & 63;
  const int w    = tid >> 6;
  const int quad = lane >> 4, l16 = lane & 15;
  const int rb   = w * 32;              // wave's q-row base within tile
  const int pbase = w * 2048;           // wave's private P region (32x64)
  const int bh = blockIdx.y;
  const int b  = bh >> 4, h = bh & 15;
  const float scale = 0.08838834764831845f;   // 1/sqrt(128)
  const float NEG = -3.0e4f;                  // finite mask value, exp -> 0

  for (int half = 0; half < 2; half++) {
    const int qi = half ? (15 - (int)blockIdx.x) : (int)blockIdx.x;
    const int q0 = qi * 128;

    // Q fragments (A-operand: m=l16, k=quad*8+e, dk selects k-32-group)
    bf16x8 aq[2][4];
    {
      const bf16* qb = Qg + ((size_t)(b * 2048 + q0 + rb + l16)) * 2048 + h * 128 + quad * 8;
#pragma unroll
      for (int i = 0; i < 2; i++)
#pragma unroll
        for (int dk = 0; dk < 4; dk++)
          aq[i][dk] = *(const bf16x8*)(qb + (size_t)i * 16 * 2048 + dk * 32);
    }

    float m_reg[2][4], l_reg[2][4];
#pragma unroll
    for (int i = 0; i < 2; i++)
#pragma unroll
      for (int r = 0; r < 4; r++) { m_reg[i][r] = NEG; l_reg[i][r] = 0.0f; }

    f32x4 o[2][8] = {};   // rows i*16+quad*4+r, d-cols j*16+l16

    const int ntiles = 2 * qi + 2;
    for (int kt = 0; kt < ntiles; kt++) {
      const int kk0 = kt * 64;
      // cooperative stage: K (64x128) and V^T (128x64), XOR-swizzled chunks
#pragma unroll
      for (int it = 0; it < 4; it++) {
        int c = tid + it * 256;
        int rk = c >> 4, ck = (c & 15) ^ (rk & 15);
        gld16(Kg + ((size_t)(b * 2048 + kk0 + rk)) * 128 + ck * 8, &Ks[c * 8]);
        int rv = c >> 3, cv = (c & 7) ^ (rv & 7);
        gld16(Vtg + ((size_t)(b * 128 + rv)) * 2048 + kk0 + cv * 8, &Vs[c * 8]);
      }
      __syncthreads();   // B1: staging visible

      if (kk0 <= q0 + rb + 31) {   // wave-uniform: skip fully-masked tiles
        // S = Q K^T : 32 q-rows x 64 keys per wave
        f32x4 s[2][4] = {};
#pragma unroll
        for (int dk = 0; dk < 4; dk++) {
          bf16x8 bk[4];
#pragma unroll
          for (int j = 0; j < 4; j++) {
            int row = j * 16 + l16;   // key index
            bk[j] = *(const bf16x8*)&Ks[(row * 16 + ((dk * 4 + quad) ^ (row & 15))) * 8];
          }
#pragma unroll
          for (int i = 0; i < 2; i++)
#pragma unroll
            for (int j = 0; j < 4; j++)
              s[i][j] = __builtin_amdgcn_mfma_f32_16x16x32_bf16(aq[i][dk], bk[j], s[i][j], 0, 0, 0);
        }

        // scale + causal mask
        const bool masked_tile = (kk0 + 63 > q0 + rb);
#pragma unroll
        for (int i = 0; i < 2; i++)
#pragma unroll
          for (int j = 0; j < 4; j++)
#pragma unroll
            for (int r = 0; r < 4; r++) {
              float v = s[i][j][r] * scale;
              if (masked_tile) {
                int rg = q0 + rb + i * 16 + quad * 4 + r;
                int cg = kk0 + j * 16 + l16;
                if (cg > rg) v = NEG;
              }
              s[i][j][r] = v;
            }

        // wave-local online softmax; write P into private LDS (A-layout swizzle)
#pragma unroll
        for (int i = 0; i < 2; i++)
#pragma unroll
          for (int r = 0; r < 4; r++) {
            float mx = fmaxf(fmaxf(s[i][0][r], s[i][1][r]), fmaxf(s[i][2][r], s[i][3][r]));
#pragma unroll
            for (int t = 1; t < 16; t <<= 1) mx = fmaxf(mx, __shfl_xor(mx, t, 64));
            float mo = m_reg[i][r];
            float mn = fmaxf(mo, mx);
            float alpha = __expf(mo - mn);
            int row = i * 16 + quad * 4 + r;
            float rs = 0.0f;
#pragma unroll
            for (int j = 0; j < 4; j++) {
              float p = __expf(s[i][j][r] - mn);
              rs += p;
              int col = j * 16 + l16;
              Ps[pbase + (row * 8 + ((col >> 3) ^ (row & 7))) * 8 + (col & 7)] = (bf16)p;
            }
#pragma unroll
            for (int t = 1; t < 16; t <<= 1) rs += __shfl_xor(rs, t, 64);
            l_reg[i][r] = l_reg[i][r] * alpha + rs;
            m_reg[i][r] = mn;
#pragma unroll
            for (int j = 0; j < 8; j++) o[i][j][r] *= alpha;
          }

        // O += P @ V  (P private-wave A-operand; V^T B-operand; lgkmcnt only)
#pragma unroll
        for (int kkt = 0; kkt < 2; kkt++) {
          bf16x8 ap[2], bv[8];
#pragma unroll
          for (int i = 0; i < 2; i++) {
            int row = i * 16 + l16;
            ap[i] = *(const bf16x8*)&Ps[pbase + (row * 8 + ((kkt * 4 + quad) ^ (row & 7))) * 8];
          }
#pragma unroll
          for (int j = 0; j < 8; j++) {
            int row = j * 16 + l16;   // d index
            bv[j] = *(const bf16x8*)&Vs[(row * 8 + ((kkt * 4 + quad) ^ (row & 7))) * 8];
          }
#pragma unroll
          for (int i = 0; i < 2; i++)
#pragma unroll
            for (int j = 0; j < 8; j++)
              o[i][j] = __builtin_amdgcn_mfma_f32_16x16x32_bf16(ap[i], bv[j], o[i][j], 0, 0, 0);
        }
      }
      __syncthreads();   // B2: all waves done with Ks/Vs; safe to restage
    }

    // epilogue: O /= l, store bf16 (b, s, h, d) — in-place over own Q region
#pragma unroll
    for (int i = 0; i < 2; i++)
#pragma unroll
      for (int r = 0; r < 4; r++) {
        int row = rb + i * 16 + quad * 4 + r;
        float l = l_reg[i][r];
        float inv = (l > 0.0f) ? 1.0f / l : 0.0f;
        size_t base = ((size_t)(b * 2048 + q0 + row)) * 2048 + h * 128;
#pragma unroll
        for (int j = 0; j < 8; j++)
          AO[base + j * 16 + l16] = (bf16)(o[i][j][r] * inv);
      }
  }
}

// ---------------------------------------------------------------------------
// Memory plan.  Inputs/outputs are fp32 (confirmed round 4).
//   d_ws  (>=32 MB known-safe): Qg/AO @0 (32 MB, in-place);
//         if ws_size >= 40.25 MB: wo_b @32M (8 MB) + ob_b @40M (4 KB)
//   d_out (64 MB fp32, dead until O-proj): Xb @0 (32 MB), Kg @32M (2 MB),
//         Vtg @34M (2 MB), wq_b @36M (8 MB), wkv_b @44M (1 MB),
//         qb_b @45M (4 KB), kvb_b @45M+4K (512 B)
// Order: cvt -> Q-proj -> KV-proj -> attention -> O-proj (overwrites d_out).
// ---------------------------------------------------------------------------
extern "C" void kernel_launch(void* const* d_in, const int* in_sizes, int n_in,
                              void* d_out, int out_size, void* d_ws, size_t ws_size,
                              hipStream_t stream)
{
  const float* X   = (const float*)d_in[0];
  const float* q_w = (const float*)d_in[1];
  const float* q_b = (const float*)d_in[2];
  const float* k_w = (const float*)d_in[3];
  const float* k_b = (const float*)d_in[4];
  const float* v_w = (const float*)d_in[5];
  const float* v_b = (const float*)d_in[6];
  const float* o_w = (const float*)d_in[7];
  const float* o_b = (const float*)d_in[8];

  char* outc = (char*)d_out;
  bf16* Xb    = (bf16*)(outc);                       // 8192 x 2048
  bf16* Kg    = (bf16*)(outc + 33554432);            // 8192 x 128 (b,s,d)
  bf16* Vtg   = (bf16*)(outc + 35651584);            // 4 x 128 x 2048 V^T
  bf16* wq_b  = (bf16*)(outc + 37748736);            // 2048 x 2048
  bf16* wkv_b = (bf16*)(outc + 46137344);            // 256 x 2048 (K rows 0-127, V 128-255)
  bf16* qb_b  = (bf16*)(outc + 47185920);            // 2048
  bf16* kvb_b = (bf16*)(outc + 47190016);            // 256

  bf16* Qg = (bf16*)d_ws;                            // 8192 x 2048; AO in-place
  bf16* AO = Qg;

  const bool big_ws = ws_size >= (size_t)(33554432 + 8388608 + 8192);
  bf16* wo_b = big_ws ? (bf16*)((char*)d_ws + 33554432) : nullptr;
  bf16* ob_b = big_ws ? (bf16*)((char*)d_ws + 41943040) : nullptr;

  CvtSegs segs;
  int n = 0;
  segs.src[n] = X;   segs.dst[n] = Xb;            segs.cnt[n] = 16777216; n++;
  segs.src[n] = q_w; segs.dst[n] = wq_b;          segs.cnt[n] = 4194304;  n++;
  segs.src[n] = k_w; segs.dst[n] = wkv_b;         segs.cnt[n] = 262144;   n++;
  segs.src[n] = v_w; segs.dst[n] = wkv_b + 262144; segs.cnt[n] = 262144;  n++;
  segs.src[n] = q_b; segs.dst[n] = qb_b;          segs.cnt[n] = 2048;     n++;
  segs.src[n] = k_b; segs.dst[n] = kvb_b;         segs.cnt[n] = 128;      n++;
  segs.src[n] = v_b; segs.dst[n] = kvb_b + 128;   segs.cnt[n] = 128;      n++;
  if (big_ws) {
    segs.src[n] = o_w; segs.dst[n] = wo_b;        segs.cnt[n] = 4194304;  n++;
    segs.src[n] = o_b; segs.dst[n] = ob_b;        segs.cnt[n] = 2048;     n++;
  }
  segs.n = n;

  dim3 blk(256);
  cvt_kernel<<<dim3(1024), blk, 0, stream>>>(segs);
  gemm_bt<<<dim3(64, 16), blk, 0, stream>>>(Xb, wq_b, qb_b, Qg, 8192, 2048, 2048, 0, 0, 0);
  gemm_bt<<<dim3(64, 2),  blk, 0, stream>>>(Xb, wkv_b, kvb_b, Kg, 8192, 256, 2048, 0, 0, 3);
  mqa_attn<<<dim3(8, 64), blk, 0, stream>>>(Qg, Kg, Vtg, AO);
  if (big_ws)
    gemm_bt<<<dim3(64, 16), blk, 0, stream>>>(AO, wo_b, ob_b, d_out, 8192, 2048, 2048, 0, 0, 2);
  else
    gemm_bt<<<dim3(64, 16), blk, 0, stream>>>(AO, o_w, o_b, d_out, 8192, 2048, 2048, 1, 1, 2);
}

// Round 2
// 495.514 us; speedup vs baseline: 1.3075x; 1.0867x over previous
//
#include <hip/hip_runtime.h>
#include <stdint.h>

typedef __bf16 bf16;
typedef __bf16 bf16x4 __attribute__((ext_vector_type(4)));
typedef __bf16 bf16x8 __attribute__((ext_vector_type(8)));
typedef float f32x4 __attribute__((ext_vector_type(4)));
typedef short s16x4 __attribute__((ext_vector_type(4)));

using gp_t = __attribute__((address_space(1))) const void*;
using lp_t = __attribute__((address_space(3))) void*;

__device__ __forceinline__ void gld16(const void* g, void* l) {
  __builtin_amdgcn_global_load_lds((gp_t)g, (lp_t)l, 16, 0, 0);
}

// ---------------------------------------------------------------------------
// fp32 -> bf16 conversion, segment table (one kernel, grid-stride per segment)
// ---------------------------------------------------------------------------
struct CvtSegs {
  const float* src[10];
  bf16* dst[10];
  int cnt[10];     // element counts, divisible by 4
  int n;
};

__global__ void cvt_kernel(CvtSegs segs) {
  const int stride = gridDim.x * blockDim.x;
  const int t0 = blockIdx.x * blockDim.x + threadIdx.x;
  for (int s = 0; s < segs.n; s++) {
    const float4* src = (const float4*)segs.src[s];
    bf16x4* dst = (bf16x4*)segs.dst[s];
    int cnt4 = segs.cnt[s] >> 2;
    for (int idx = t0; idx < cnt4; idx += stride) {
      float4 v = src[idx];
      bf16x4 o; o[0] = (bf16)v.x; o[1] = (bf16)v.y; o[2] = (bf16)v.z; o[3] = (bf16)v.w;
      dst[idx] = o;
    }
  }
}

// ---------------------------------------------------------------------------
// C[M,N] = A[M,K] @ W[N,K]^T + bias[N]   (bf16 A via global_load_lds;
// W bf16 fast path or fp32 float4+cvt fallback).  128x128 tile, BK=64,
// XOR-swizzled LDS, m97-style 2-barrier K-loop.
// store_sel: 0 = bf16 row-major C
//            2 = fp32 row-major C (final output)
//            3 = fused KV: col<128 -> K row-major (b,s,d) at C;
//                          col>=128 -> V^T (b,d,s) at C + 1048576 elements
// ---------------------------------------------------------------------------
__global__ __launch_bounds__(256, 2)
void gemm_bt(const bf16* __restrict__ A, const void* __restrict__ Wv,
             const void* __restrict__ biasv, void* __restrict__ Cv,
             int M, int N, int K, int w_fp32, int bias_fp32, int store_sel)
{
  __shared__ __align__(16) bf16 As[128 * 64];
  __shared__ __align__(16) bf16 Bs[128 * 64];
  const int tid  = threadIdx.x;
  const int lane = tid & 63;
  const int w    = tid >> 6;
  const int wm   = w >> 1, wn = w & 1;
  const int quad = lane >> 4, l16 = lane & 15;
  const int m0 = blockIdx.x * 128, n0 = blockIdx.y * 128;

  f32x4 acc[4][4] = {};

  for (int k0 = 0; k0 < K; k0 += 64) {
#pragma unroll
    for (int it = 0; it < 4; it++) {
      int c = tid + it * 256;          // lane-contiguous LDS slots (required)
      int row = c >> 3;
      int cc  = (c & 7) ^ (row & 7);   // XOR swizzle on 16B chunks
      gld16(A + (size_t)(m0 + row) * K + k0 + cc * 8, &As[c * 8]);
      size_t woff = (size_t)(n0 + row) * K + k0 + cc * 8;
      if (!w_fp32) {
        gld16((const bf16*)Wv + woff, &Bs[c * 8]);
      } else {
        const float* Wf = (const float*)Wv;
        float4 x0 = *(const float4*)(Wf + woff);
        float4 x1 = *(const float4*)(Wf + woff + 4);
        bf16x8 v;
        v[0] = (bf16)x0.x; v[1] = (bf16)x0.y; v[2] = (bf16)x0.z; v[3] = (bf16)x0.w;
        v[4] = (bf16)x1.x; v[5] = (bf16)x1.y; v[6] = (bf16)x1.z; v[7] = (bf16)x1.w;
        *(bf16x8*)&Bs[c * 8] = v;
      }
    }
    __syncthreads();                   // drains vmcnt (gld16) + lgkmcnt
#pragma unroll
    for (int dk = 0; dk < 2; dk++) {
      bf16x8 af[4], bw[4];
#pragma unroll
      for (int i = 0; i < 4; i++) {
        int row = wm * 64 + i * 16 + l16;
        af[i] = *(const bf16x8*)&As[(row * 8 + ((dk * 4 + quad) ^ (row & 7))) * 8];
      }
#pragma unroll
      for (int j = 0; j < 4; j++) {
        int row = wn * 64 + j * 16 + l16;
        bw[j] = *(const bf16x8*)&Bs[(row * 8 + ((dk * 4 + quad) ^ (row & 7))) * 8];
      }
#pragma unroll
      for (int i = 0; i < 4; i++)
#pragma unroll
        for (int j = 0; j < 4; j++)
          acc[i][j] = __builtin_amdgcn_mfma_f32_16x16x32_bf16(af[i], bw[j], acc[i][j], 0, 0, 0);
    }
    __syncthreads();
  }

  // epilogue: C/D layout col=lane&15, row=quad*4+reg (m89/m91-verified)
#pragma unroll
  for (int j = 0; j < 4; j++) {
    int col = n0 + wn * 64 + j * 16 + l16;
    float bv = bias_fp32 ? ((const float*)biasv)[col] : (float)((const bf16*)biasv)[col];
#pragma unroll
    for (int i = 0; i < 4; i++) {
#pragma unroll
      for (int r = 0; r < 4; r++) {
        int row = m0 + wm * 64 + i * 16 + quad * 4 + r;
        float v = acc[i][j][r] + bv;
        if (store_sel == 0) {
          ((bf16*)Cv)[(size_t)row * N + col] = (bf16)v;
        } else if (store_sel == 2) {
          ((float*)Cv)[(size_t)row * N + col] = v;
        } else {   // fused KV split
          int b = row >> 11, s = row & 2047;   // S=2048 per batch
          if (col < 128) {
            ((bf16*)Cv)[(size_t)row * 128 + col] = (bf16)v;              // K (b,s,d)
          } else {
            ((bf16*)Cv + 1048576)[((size_t)(b * 128 + (col - 128))) * 2048 + s] = (bf16)v; // V^T
          }
        }
      }
    }
  }
}

// ---------------------------------------------------------------------------
// Causal MQA flash attention, v3: swapped-operand softmax + register P +
// double-buffered K/V prefetch (ONE barrier per k-tile).
// grid = (p=8, bh=64), block = 256 (4 waves); block p does qi = p and 15-p
// (constant 36 tile-iters/block, kills the causal tail).
// Per tile:
//   S^T = mfma(K,Q)  -> col = q = l16, row = key = j*16+quad*4+r.
//     Row max/sum: 15 in-reg ops + 2 shfl_xor (vs 8x(4+4) in v2).
//   P stays in REGISTERS: K=16 mfma (16x16x16bf16_1k) B-operand k-layout is
//     quad*4+e = exactly the keys this thread owns.  No Ps LDS at all.
//   O^T = mfma(V,P^T): col = q = l16 -> alpha/l rescale needs NO shuffles.
//   Rescale skipped exactly when __any(mx>m_old) is false (alpha==1).
//   Scale folded into exp2: p = exp2(s*c - m*c), c = log2e/sqrt(128).
// LDS: K/V double-buffered 2*(16+16) KB = 64 KB -> 2 blocks/CU (128 KB).
// Prefetch tile t+1 issued BEFORE compute of tile t; the single
// __syncthreads() at tile end drains it after a full compute phase.
// AO aliases Qg in place (block touches only its own two Q tiles).
// ---------------------------------------------------------------------------
__global__ __launch_bounds__(256, 2)
void mqa_attn(const bf16* Qg, const bf16* __restrict__ Kg,
              const bf16* __restrict__ Vtg, bf16* AO)
{
  __shared__ __align__(16) bf16 Ks[2][64 * 128];
  __shared__ __align__(16) bf16 Vs[2][128 * 64];

  const int tid  = threadIdx.x;
  const int lane = tid & 63;
  const int w    = tid >> 6;
  const int quad = lane >> 4, l16 = lane & 15;
  const int rb   = w * 32;              // wave's q-row base within tile
  const int bh = blockIdx.y;
  const int b  = bh >> 4, h = bh & 15;
  const float C2  = 0.12751879526288147f;   // log2(e)/sqrt(128)
  const float NEG = -3.0e4f;                // finite mask value, exp2 -> 0

  for (int half = 0; half < 2; half++) {
    const int qi = half ? (15 - (int)blockIdx.x) : (int)blockIdx.x;
    const int q0 = qi * 128;

    // Q fragments (lane l16 = q-row, k = quad*8+e, dk = k-32-group)
    bf16x8 aq[2][4];
    {
      const bf16* qb = Qg + ((size_t)(b * 2048 + q0 + rb + l16)) * 2048 + h * 128 + quad * 8;
#pragma unroll
      for (int i = 0; i < 2; i++)
#pragma unroll
        for (int dk = 0; dk < 4; dk++)
          aq[i][dk] = *(const bf16x8*)(qb + (size_t)i * 16 * 2048 + dk * 32);
    }

    float m_reg[2] = {NEG, NEG};       // per q = i*16+l16 (replicated x4 quads)
    float l_reg[2] = {0.0f, 0.0f};
    f32x4 ot[2][8] = {};               // O^T: [i][jd], q=i*16+l16, d=jd*16+quad*4+r

    const int nt = 2 * qi + 2;

    // stage tile 0 into buffer 0
#pragma unroll
    for (int it = 0; it < 4; it++) {
      int c = tid + it * 256;
      int rk = c >> 4, ck = (c & 15) ^ (rk & 15);
      gld16(Kg + ((size_t)(b * 2048 + rk)) * 128 + ck * 8, &Ks[0][c * 8]);
      int rv = c >> 3, cv = (c & 7) ^ (rv & 7);
      gld16(Vtg + ((size_t)(b * 128 + rv)) * 2048 + cv * 8, &Vs[0][c * 8]);
    }
    __syncthreads();

    int cur = 0;
    for (int kt = 0; kt < nt; kt++) {
      const int kk0 = kt * 64;

      // prefetch next tile into other buffer; flies during compute below
      if (kt + 1 < nt) {
        const int nk0 = kk0 + 64;
#pragma unroll
        for (int it = 0; it < 4; it++) {
          int c = tid + it * 256;
          int rk = c >> 4, ck = (c & 15) ^ (rk & 15);
          gld16(Kg + ((size_t)(b * 2048 + nk0 + rk)) * 128 + ck * 8, &Ks[cur ^ 1][c * 8]);
          int rv = c >> 3, cv = (c & 7) ^ (rv & 7);
          gld16(Vtg + ((size_t)(b * 128 + rv)) * 2048 + nk0 + cv * 8, &Vs[cur ^ 1][c * 8]);
        }
      }

      if (kk0 <= q0 + rb + 31) {   // wave-uniform: skip fully-masked tiles
        // S^T = K Q^T : st[j][i] col=q=l16, row=key=j*16+quad*4+r
        f32x4 st[4][2] = {};
#pragma unroll
        for (int dk = 0; dk < 4; dk++) {
          bf16x8 bk[4];
#pragma unroll
          for (int j = 0; j < 4; j++) {
            int row = j * 16 + l16;   // key index
            bk[j] = *(const bf16x8*)&Ks[cur][(row * 16 + ((dk * 4 + quad) ^ (row & 15))) * 8];
          }
#pragma unroll
          for (int j = 0; j < 4; j++)
#pragma unroll
            for (int i = 0; i < 2; i++)
              st[j][i] = __builtin_amdgcn_mfma_f32_16x16x32_bf16(bk[j], aq[i][dk], st[j][i], 0, 0, 0);
        }

        if (kk0 + 63 > q0 + rb) {   // diagonal tile(s): causal mask (raw-s space)
#pragma unroll
          for (int j = 0; j < 4; j++)
#pragma unroll
            for (int i = 0; i < 2; i++)
#pragma unroll
              for (int r = 0; r < 4; r++) {
                int key = kk0 + j * 16 + quad * 4 + r;
                int qg  = q0 + rb + i * 16 + l16;
                if (key > qg) st[j][i][r] = NEG;
              }
        }

        // wave softmax (per i-block of 16 q-rows); P packed to bf16 in regs
        s16x4 ps[2][4];
#pragma unroll
        for (int i = 0; i < 2; i++) {
          float mx = st[0][i][0];
#pragma unroll
          for (int j = 0; j < 4; j++)
#pragma unroll
            for (int r = 0; r < 4; r++) mx = fmaxf(mx, st[j][i][r]);
          mx = fmaxf(mx, __shfl_xor(mx, 16, 64));
          mx = fmaxf(mx, __shfl_xor(mx, 32, 64));
          float mo = m_reg[i];
          if (__any(mx > mo)) {        // exact: alpha==1 when skipped
            float mn = fmaxf(mo, mx);
            float al = exp2f((mo - mn) * C2);
            l_reg[i] *= al;
#pragma unroll
            for (int jd = 0; jd < 8; jd++)
#pragma unroll
              for (int r = 0; r < 4; r++) ot[i][jd][r] *= al;
            m_reg[i] = mn;
          }
          float mc = m_reg[i] * C2;
          float rs = 0.0f;
#pragma unroll
          for (int j = 0; j < 4; j++) {
            float p0 = exp2f(st[j][i][0] * C2 - mc);
            float p1 = exp2f(st[j][i][1] * C2 - mc);
            float p2 = exp2f(st[j][i][2] * C2 - mc);
            float p3 = exp2f(st[j][i][3] * C2 - mc);
            rs += (p0 + p1) + (p2 + p3);
            union { bf16x4 h; s16x4 s; } pu;
            pu.h[0] = (bf16)p0; pu.h[1] = (bf16)p1;
            pu.h[2] = (bf16)p2; pu.h[3] = (bf16)p3;
            ps[i][j] = pu.s;
          }
          rs += __shfl_xor(rs, 16, 64);
          rs += __shfl_xor(rs, 32, 64);
          l_reg[i] += rs;
        }

        // O^T += V^T P^T : K=16 MFMAs; A=V-frag (m=d=l16, k=quad*4+e),
        // B=P^T-frag = this thread's own keys. No LDS for P.
#pragma unroll
        for (int jd = 0; jd < 8; jd++) {
          int vrow = jd * 16 + l16;   // d index
#pragma unroll
          for (int jk = 0; jk < 4; jk++) {
            int vch = (jk * 2 + (quad >> 1)) ^ (vrow & 7);
            s16x4 vf = *(const s16x4*)&Vs[cur][(vrow * 8 + vch) * 8 + (quad & 1) * 4];
#pragma unroll
            for (int i = 0; i < 2; i++)
              ot[i][jd] = __builtin_amdgcn_mfma_f32_16x16x16bf16_1k(vf, ps[i][jk], ot[i][jd], 0, 0, 0);
          }
        }
      }
      __syncthreads();   // prefetch drained + all waves done with buffers[cur]
      cur ^= 1;
    }

    // epilogue: O^T / l, store bf16 (b,s,h,d); l indexed by l16 = q (no shuffle)
#pragma unroll
    for (int i = 0; i < 2; i++) {
      float l = l_reg[i];
      float inv = (l > 0.0f) ? 1.0f / l : 0.0f;
      size_t base = ((size_t)(b * 2048 + q0 + rb + i * 16 + l16)) * 2048 + h * 128 + quad * 4;
#pragma unroll
      for (int jd = 0; jd < 8; jd++) {
        bf16x4 ov;
#pragma unroll
        for (int r = 0; r < 4; r++) ov[r] = (bf16)(ot[i][jd][r] * inv);
        *(bf16x4*)(AO + base + jd * 16) = ov;
      }
    }
  }
}

// ---------------------------------------------------------------------------
// Memory plan.  Inputs/outputs are fp32.
//   d_ws  (>=32 MB known-safe): Qg/AO @0 (32 MB, in-place);
//         if ws_size >= 40.25 MB: wo_b @32M (8 MB) + ob_b @40M (4 KB)
//   d_out (64 MB fp32, dead until O-proj): Xb @0 (32 MB), Kg @32M (2 MB),
//         Vtg @34M (2 MB), wq_b @36M (8 MB), wkv_b @44M (1 MB),
//         qb_b @45M (4 KB), kvb_b @45M+4K (512 B)
// Order: cvt -> Q-proj -> KV-proj -> attention -> O-proj (overwrites d_out).
// ---------------------------------------------------------------------------
extern "C" void kernel_launch(void* const* d_in, const int* in_sizes, int n_in,
                              void* d_out, int out_size, void* d_ws, size_t ws_size,
                              hipStream_t stream)
{
  const float* X   = (const float*)d_in[0];
  const float* q_w = (const float*)d_in[1];
  const float* q_b = (const float*)d_in[2];
  const float* k_w = (const float*)d_in[3];
  const float* k_b = (const float*)d_in[4];
  const float* v_w = (const float*)d_in[5];
  const float* v_b = (const float*)d_in[6];
  const float* o_w = (const float*)d_in[7];
  const float* o_b = (const float*)d_in[8];

  char* outc = (char*)d_out;
  bf16* Xb    = (bf16*)(outc);                       // 8192 x 2048
  bf16* Kg    = (bf16*)(outc + 33554432);            // 8192 x 128 (b,s,d)
  bf16* Vtg   = (bf16*)(outc + 35651584);            // 4 x 128 x 2048 V^T
  bf16* wq_b  = (bf16*)(outc + 37748736);            // 2048 x 2048
  bf16* wkv_b = (bf16*)(outc + 46137344);            // 256 x 2048 (K rows 0-127, V 128-255)
  bf16* qb_b  = (bf16*)(outc + 47185920);            // 2048
  bf16* kvb_b = (bf16*)(outc + 47190016);            // 256

  bf16* Qg = (bf16*)d_ws;                            // 8192 x 2048; AO in-place
  bf16* AO = Qg;

  const bool big_ws = ws_size >= (size_t)(33554432 + 8388608 + 8192);
  bf16* wo_b = big_ws ? (bf16*)((char*)d_ws + 33554432) : nullptr;
  bf16* ob_b = big_ws ? (bf16*)((char*)d_ws + 41943040) : nullptr;

  CvtSegs segs;
  int n = 0;
  segs.src[n] = X;   segs.dst[n] = Xb;            segs.cnt[n] = 16777216; n++;
  segs.src[n] = q_w; segs.dst[n] = wq_b;          segs.cnt[n] = 4194304;  n++;
  segs.src[n] = k_w; segs.dst[n] = wkv_b;         segs.cnt[n] = 262144;   n++;
  segs.src[n] = v_w; segs.dst[n] = wkv_b + 262144; segs.cnt[n] = 262144;  n++;
  segs.src[n] = q_b; segs.dst[n] = qb_b;          segs.cnt[n] = 2048;     n++;
  segs.src[n] = k_b; segs.dst[n] = kvb_b;         segs.cnt[n] = 128;      n++;
  segs.src[n] = v_b; segs.dst[n] = kvb_b + 128;   segs.cnt[n] = 128;      n++;
  if (big_ws) {
    segs.src[n] = o_w; segs.dst[n] = wo_b;        segs.cnt[n] = 4194304;  n++;
    segs.src[n] = o_b; segs.dst[n] = ob_b;        segs.cnt[n] = 2048;     n++;
  }
  segs.n = n;

  dim3 blk(256);
  cvt_kernel<<<dim3(1024), blk, 0, stream>>>(segs);
  gemm_bt<<<dim3(64, 16), blk, 0, stream>>>(Xb, wq_b, qb_b, Qg, 8192, 2048, 2048, 0, 0, 0);
  gemm_bt<<<dim3(64, 2),  blk, 0, stream>>>(Xb, wkv_b, kvb_b, Kg, 8192, 256, 2048, 0, 0, 3);
  mqa_attn<<<dim3(8, 64), blk, 0, stream>>>(Qg, Kg, Vtg, AO);
  if (big_ws)
    gemm_bt<<<dim3(64, 16), blk, 0, stream>>>(AO, wo_b, ob_b, d_out, 8192, 2048, 2048, 0, 0, 2);
  else
    gemm_bt<<<dim3(64, 16), blk, 0, stream>>>(AO, o_w, o_b, d_out, 8192, 2048, 2048, 1, 1, 2);
}

// Round 3
// 488.581 us; speedup vs baseline: 1.3260x; 1.0142x over previous
//
#include <hip/hip_runtime.h>
#include <stdint.h>

typedef __bf16 bf16;
typedef __bf16 bf16x4 __attribute__((ext_vector_type(4)));
typedef __bf16 bf16x8 __attribute__((ext_vector_type(8)));
typedef float f32x4 __attribute__((ext_vector_type(4)));
typedef short s16x4 __attribute__((ext_vector_type(4)));

using gp_t = __attribute__((address_space(1))) const void*;
using lp_t = __attribute__((address_space(3))) void*;

__device__ __forceinline__ void gld16(const void* g, void* l) {
  __builtin_amdgcn_global_load_lds((gp_t)g, (lp_t)l, 16, 0, 0);
}

// ---------------------------------------------------------------------------
// fp32 -> bf16 conversion, segment table (one kernel, grid-stride per segment)
// ---------------------------------------------------------------------------
struct CvtSegs {
  const float* src[10];
  bf16* dst[10];
  int cnt[10];     // element counts, divisible by 4
  int n;
};

__global__ void cvt_kernel(CvtSegs segs) {
  const int stride = gridDim.x * blockDim.x;
  const int t0 = blockIdx.x * blockDim.x + threadIdx.x;
  for (int s = 0; s < segs.n; s++) {
    const float4* src = (const float4*)segs.src[s];
    bf16x4* dst = (bf16x4*)segs.dst[s];
    int cnt4 = segs.cnt[s] >> 2;
    for (int idx = t0; idx < cnt4; idx += stride) {
      float4 v = src[idx];
      bf16x4 o; o[0] = (bf16)v.x; o[1] = (bf16)v.y; o[2] = (bf16)v.z; o[3] = (bf16)v.w;
      dst[idx] = o;
    }
  }
}

// ---------------------------------------------------------------------------
// C[M,N] = A[M,K] @ W[N,K]^T + bias[N]   (bf16 A via global_load_lds;
// W bf16 fast path or fp32 float4+cvt fallback).  128x128 tile, BK=64,
// XOR-swizzled LDS, m97-style 2-barrier K-loop.
// store_sel: 0 = bf16 row-major C (stride N)
//            2 = fp32 row-major C (final output, stride N)
//            4 = fused QKV: col<2048  -> Q bf16 (row stride 2048) at Cv
//                           col<2176  -> K (b,s,d) bf16 at Cv2
//                           else      -> V^T (b,d,s) bf16 at Cv3
//                (branches are block-uniform: y-tile 0-15 Q, 16 K, 17 V)
// ---------------------------------------------------------------------------
__global__ __launch_bounds__(256, 2)
void gemm_bt(const bf16* __restrict__ A, const void* __restrict__ Wv,
             const void* __restrict__ biasv, void* __restrict__ Cv,
             void* __restrict__ Cv2, void* __restrict__ Cv3,
             int M, int N, int K, int w_fp32, int bias_fp32, int store_sel)
{
  __shared__ __align__(16) bf16 As[128 * 64];
  __shared__ __align__(16) bf16 Bs[128 * 64];
  const int tid  = threadIdx.x;
  const int lane = tid & 63;
  const int w    = tid >> 6;
  const int wm   = w >> 1, wn = w & 1;
  const int quad = lane >> 4, l16 = lane & 15;
  const int m0 = blockIdx.x * 128, n0 = blockIdx.y * 128;

  f32x4 acc[4][4] = {};

  for (int k0 = 0; k0 < K; k0 += 64) {
#pragma unroll
    for (int it = 0; it < 4; it++) {
      int c = tid + it * 256;          // lane-contiguous LDS slots (required)
      int row = c >> 3;
      int cc  = (c & 7) ^ (row & 7);   // XOR swizzle on 16B chunks
      gld16(A + (size_t)(m0 + row) * K + k0 + cc * 8, &As[c * 8]);
      size_t woff = (size_t)(n0 + row) * K + k0 + cc * 8;
      if (!w_fp32) {
        gld16((const bf16*)Wv + woff, &Bs[c * 8]);
      } else {
        const float* Wf = (const float*)Wv;
        float4 x0 = *(const float4*)(Wf + woff);
        float4 x1 = *(const float4*)(Wf + woff + 4);
        bf16x8 v;
        v[0] = (bf16)x0.x; v[1] = (bf16)x0.y; v[2] = (bf16)x0.z; v[3] = (bf16)x0.w;
        v[4] = (bf16)x1.x; v[5] = (bf16)x1.y; v[6] = (bf16)x1.z; v[7] = (bf16)x1.w;
        *(bf16x8*)&Bs[c * 8] = v;
      }
    }
    __syncthreads();                   // drains vmcnt (gld16) + lgkmcnt
#pragma unroll
    for (int dk = 0; dk < 2; dk++) {
      bf16x8 af[4], bw[4];
#pragma unroll
      for (int i = 0; i < 4; i++) {
        int row = wm * 64 + i * 16 + l16;
        af[i] = *(const bf16x8*)&As[(row * 8 + ((dk * 4 + quad) ^ (row & 7))) * 8];
      }
#pragma unroll
      for (int j = 0; j < 4; j++) {
        int row = wn * 64 + j * 16 + l16;
        bw[j] = *(const bf16x8*)&Bs[(row * 8 + ((dk * 4 + quad) ^ (row & 7))) * 8];
      }
      __builtin_amdgcn_s_setprio(1);
#pragma unroll
      for (int i = 0; i < 4; i++)
#pragma unroll
        for (int j = 0; j < 4; j++)
          acc[i][j] = __builtin_amdgcn_mfma_f32_16x16x32_bf16(af[i], bw[j], acc[i][j], 0, 0, 0);
      __builtin_amdgcn_s_setprio(0);
    }
    __syncthreads();
  }

  // epilogue: C/D layout col=lane&15, row=quad*4+reg (m89/m91-verified)
#pragma unroll
  for (int j = 0; j < 4; j++) {
    int col = n0 + wn * 64 + j * 16 + l16;
    float bv = bias_fp32 ? ((const float*)biasv)[col] : (float)((const bf16*)biasv)[col];
#pragma unroll
    for (int i = 0; i < 4; i++) {
#pragma unroll
      for (int r = 0; r < 4; r++) {
        int row = m0 + wm * 64 + i * 16 + quad * 4 + r;
        float v = acc[i][j][r] + bv;
        if (store_sel == 0) {
          ((bf16*)Cv)[(size_t)row * N + col] = (bf16)v;
        } else if (store_sel == 2) {
          ((float*)Cv)[(size_t)row * N + col] = v;
        } else {   // fused QKV split
          if (col < 2048) {
            ((bf16*)Cv)[(size_t)row * 2048 + col] = (bf16)v;             // Q (b,s,h,d)
          } else if (col < 2176) {
            ((bf16*)Cv2)[(size_t)row * 128 + (col - 2048)] = (bf16)v;    // K (b,s,d)
          } else {
            int b = row >> 11, s = row & 2047;   // S=2048 per batch
            ((bf16*)Cv3)[((size_t)(b * 128 + (col - 2176))) * 2048 + s] = (bf16)v; // V^T
          }
        }
      }
    }
  }
}

// ---------------------------------------------------------------------------
// Causal MQA flash attention, v3: swapped-operand softmax + register P +
// double-buffered K/V prefetch (ONE barrier per k-tile) + setprio on MFMA.
// grid = (p=8, bh=64), block = 256 (4 waves); block p does qi = p and 15-p
// (constant 36 tile-iters/block, kills the causal tail).
// Per tile:
//   S^T = mfma(K,Q)  -> col = q = l16, row = key = j*16+quad*4+r.
//   P stays in REGISTERS: K=16 mfma (16x16x16bf16_1k) B-operand k-layout is
//     quad*4+e = exactly the keys this thread owns.  No Ps LDS at all.
//   O^T = mfma(V,P^T): col = q = l16 -> alpha/l rescale needs NO shuffles.
//   Rescale skipped exactly when __any(mx>m_old) is false (alpha==1).
//   Scale folded into exp2: p = exp2(s*c - m*c), c = log2e/sqrt(128).
// LDS: K/V double-buffered 2*(16+16) KB = 64 KB -> 2 blocks/CU.
// AO aliases Qg in place (block touches only its own two Q tiles).
// ---------------------------------------------------------------------------
__global__ __launch_bounds__(256, 2)
void mqa_attn(const bf16* Qg, const bf16* __restrict__ Kg,
              const bf16* __restrict__ Vtg, bf16* AO)
{
  __shared__ __align__(16) bf16 Ks[2][64 * 128];
  __shared__ __align__(16) bf16 Vs[2][128 * 64];

  const int tid  = threadIdx.x;
  const int lane = tid & 63;
  const int w    = tid >> 6;
  const int quad = lane >> 4, l16 = lane & 15;
  const int rb   = w * 32;              // wave's q-row base within tile
  const int bh = blockIdx.y;
  const int b  = bh >> 4, h = bh & 15;
  const float C2  = 0.12751879526288147f;   // log2(e)/sqrt(128)
  const float NEG = -3.0e4f;                // finite mask value, exp2 -> 0

  for (int half = 0; half < 2; half++) {
    const int qi = half ? (15 - (int)blockIdx.x) : (int)blockIdx.x;
    const int q0 = qi * 128;

    // Q fragments (lane l16 = q-row, k = quad*8+e, dk = k-32-group)
    bf16x8 aq[2][4];
    {
      const bf16* qb = Qg + ((size_t)(b * 2048 + q0 + rb + l16)) * 2048 + h * 128 + quad * 8;
#pragma unroll
      for (int i = 0; i < 2; i++)
#pragma unroll
        for (int dk = 0; dk < 4; dk++)
          aq[i][dk] = *(const bf16x8*)(qb + (size_t)i * 16 * 2048 + dk * 32);
    }

    float m_reg[2] = {NEG, NEG};       // per q = i*16+l16 (replicated x4 quads)
    float l_reg[2] = {0.0f, 0.0f};
    f32x4 ot[2][8] = {};               // O^T: [i][jd], q=i*16+l16, d=jd*16+quad*4+r

    const int nt = 2 * qi + 2;

    // stage tile 0 into buffer 0
#pragma unroll
    for (int it = 0; it < 4; it++) {
      int c = tid + it * 256;
      int rk = c >> 4, ck = (c & 15) ^ (rk & 15);
      gld16(Kg + ((size_t)(b * 2048 + rk)) * 128 + ck * 8, &Ks[0][c * 8]);
      int rv = c >> 3, cv = (c & 7) ^ (rv & 7);
      gld16(Vtg + ((size_t)(b * 128 + rv)) * 2048 + cv * 8, &Vs[0][c * 8]);
    }
    __syncthreads();

    int cur = 0;
    for (int kt = 0; kt < nt; kt++) {
      const int kk0 = kt * 64;

      // prefetch next tile into other buffer; flies during compute below
      if (kt + 1 < nt) {
        const int nk0 = kk0 + 64;
#pragma unroll
        for (int it = 0; it < 4; it++) {
          int c = tid + it * 256;
          int rk = c >> 4, ck = (c & 15) ^ (rk & 15);
          gld16(Kg + ((size_t)(b * 2048 + nk0 + rk)) * 128 + ck * 8, &Ks[cur ^ 1][c * 8]);
          int rv = c >> 3, cv = (c & 7) ^ (rv & 7);
          gld16(Vtg + ((size_t)(b * 128 + rv)) * 2048 + nk0 + cv * 8, &Vs[cur ^ 1][c * 8]);
        }
      }

      if (kk0 <= q0 + rb + 31) {   // wave-uniform: skip fully-masked tiles
        // S^T = K Q^T : st[j][i] col=q=l16, row=key=j*16+quad*4+r
        f32x4 st[4][2] = {};
#pragma unroll
        for (int dk = 0; dk < 4; dk++) {
          bf16x8 bk[4];
#pragma unroll
          for (int j = 0; j < 4; j++) {
            int row = j * 16 + l16;   // key index
            bk[j] = *(const bf16x8*)&Ks[cur][(row * 16 + ((dk * 4 + quad) ^ (row & 15))) * 8];
          }
          __builtin_amdgcn_s_setprio(1);
#pragma unroll
          for (int j = 0; j < 4; j++)
#pragma unroll
            for (int i = 0; i < 2; i++)
              st[j][i] = __builtin_amdgcn_mfma_f32_16x16x32_bf16(bk[j], aq[i][dk], st[j][i], 0, 0, 0);
          __builtin_amdgcn_s_setprio(0);
        }

        if (kk0 + 63 > q0 + rb) {   // diagonal tile(s): causal mask (raw-s space)
#pragma unroll
          for (int j = 0; j < 4; j++)
#pragma unroll
            for (int i = 0; i < 2; i++)
#pragma unroll
              for (int r = 0; r < 4; r++) {
                int key = kk0 + j * 16 + quad * 4 + r;
                int qg  = q0 + rb + i * 16 + l16;
                if (key > qg) st[j][i][r] = NEG;
              }
        }

        // wave softmax (per i-block of 16 q-rows); P packed to bf16 in regs
        s16x4 ps[2][4];
#pragma unroll
        for (int i = 0; i < 2; i++) {
          float mx = st[0][i][0];
#pragma unroll
          for (int j = 0; j < 4; j++)
#pragma unroll
            for (int r = 0; r < 4; r++) mx = fmaxf(mx, st[j][i][r]);
          mx = fmaxf(mx, __shfl_xor(mx, 16, 64));
          mx = fmaxf(mx, __shfl_xor(mx, 32, 64));
          float mo = m_reg[i];
          if (__any(mx > mo)) {        // exact: alpha==1 when skipped
            float mn = fmaxf(mo, mx);
            float al = exp2f((mo - mn) * C2);
            l_reg[i] *= al;
#pragma unroll
            for (int jd = 0; jd < 8; jd++)
#pragma unroll
              for (int r = 0; r < 4; r++) ot[i][jd][r] *= al;
            m_reg[i] = mn;
          }
          float mc = m_reg[i] * C2;
          float rs = 0.0f;
#pragma unroll
          for (int j = 0; j < 4; j++) {
            float p0 = exp2f(st[j][i][0] * C2 - mc);
            float p1 = exp2f(st[j][i][1] * C2 - mc);
            float p2 = exp2f(st[j][i][2] * C2 - mc);
            float p3 = exp2f(st[j][i][3] * C2 - mc);
            rs += (p0 + p1) + (p2 + p3);
            union { bf16x4 h; s16x4 s; } pu;
            pu.h[0] = (bf16)p0; pu.h[1] = (bf16)p1;
            pu.h[2] = (bf16)p2; pu.h[3] = (bf16)p3;
            ps[i][j] = pu.s;
          }
          rs += __shfl_xor(rs, 16, 64);
          rs += __shfl_xor(rs, 32, 64);
          l_reg[i] += rs;
        }

        // O^T += V^T P^T : K=16 MFMAs; A=V-frag (m=d=l16, k=quad*4+e),
        // B=P^T-frag = this thread's own keys. No LDS for P.
#pragma unroll
        for (int jd = 0; jd < 8; jd++) {
          int vrow = jd * 16 + l16;   // d index
          s16x4 vf[4];
#pragma unroll
          for (int jk = 0; jk < 4; jk++) {
            int vch = (jk * 2 + (quad >> 1)) ^ (vrow & 7);
            vf[jk] = *(const s16x4*)&Vs[cur][(vrow * 8 + vch) * 8 + (quad & 1) * 4];
          }
          __builtin_amdgcn_s_setprio(1);
#pragma unroll
          for (int jk = 0; jk < 4; jk++)
#pragma unroll
            for (int i = 0; i < 2; i++)
              ot[i][jd] = __builtin_amdgcn_mfma_f32_16x16x16bf16_1k(vf[jk], ps[i][jk], ot[i][jd], 0, 0, 0);
          __builtin_amdgcn_s_setprio(0);
        }
      }
      __syncthreads();   // prefetch drained + all waves done with buffers[cur]
      cur ^= 1;
    }

    // epilogue: O^T / l, store bf16 (b,s,h,d); l indexed by l16 = q (no shuffle)
#pragma unroll
    for (int i = 0; i < 2; i++) {
      float l = l_reg[i];
      float inv = (l > 0.0f) ? 1.0f / l : 0.0f;
      size_t base = ((size_t)(b * 2048 + q0 + rb + i * 16 + l16)) * 2048 + h * 128 + quad * 4;
#pragma unroll
      for (int jd = 0; jd < 8; jd++) {
        bf16x4 ov;
#pragma unroll
        for (int r = 0; r < 4; r++) ov[r] = (bf16)(ot[i][jd][r] * inv);
        *(bf16x4*)(AO + base + jd * 16) = ov;
      }
    }
  }
}

// ---------------------------------------------------------------------------
// Memory plan.  Inputs/outputs are fp32.
//   d_ws  (>=32 MB known-safe): Qg/AO @0 (32 MB, in-place);
//         if ws_size >= 40.25 MB: wo_b @32M (8 MB) + ob_b @40M (4 KB)
//   d_out (64 MB fp32, dead until O-proj): Xb @0 (32 MB), Kg @32M (2 MB),
//         Vtg @34M (2 MB), wq_b @36M (8 MB), wkv_b @44M (1 MB, contiguous
//         after wq_b -> single 2304x2048 QKV weight), qb_b @45M (4 KB),
//         kvb_b right after (contiguous 2304-bias)
// Order: cvt -> fused QKV-proj -> attention -> O-proj (overwrites d_out).
// ---------------------------------------------------------------------------
extern "C" void kernel_launch(void* const* d_in, const int* in_sizes, int n_in,
                              void* d_out, int out_size, void* d_ws, size_t ws_size,
                              hipStream_t stream)
{
  const float* X   = (const float*)d_in[0];
  const float* q_w = (const float*)d_in[1];
  const float* q_b = (const float*)d_in[2];
  const float* k_w = (const float*)d_in[3];
  const float* k_b = (const float*)d_in[4];
  const float* v_w = (const float*)d_in[5];
  const float* v_b = (const float*)d_in[6];
  const float* o_w = (const float*)d_in[7];
  const float* o_b = (const float*)d_in[8];

  char* outc = (char*)d_out;
  bf16* Xb    = (bf16*)(outc);                       // 8192 x 2048
  bf16* Kg    = (bf16*)(outc + 33554432);            // 8192 x 128 (b,s,d)
  bf16* Vtg   = (bf16*)(outc + 35651584);            // 4 x 128 x 2048 V^T
  bf16* wq_b  = (bf16*)(outc + 37748736);            // 2048 x 2048
  bf16* wkv_b = (bf16*)(outc + 46137344);            // 256 x 2048 (contig after wq_b)
  bf16* qb_b  = (bf16*)(outc + 47185920);            // 2048
  bf16* kvb_b = (bf16*)(outc + 47190016);            // 256 (contig after qb_b)

  bf16* Qg = (bf16*)d_ws;                            // 8192 x 2048; AO in-place
  bf16* AO = Qg;

  const bool big_ws = ws_size >= (size_t)(33554432 + 8388608 + 8192);
  bf16* wo_b = big_ws ? (bf16*)((char*)d_ws + 33554432) : nullptr;
  bf16* ob_b = big_ws ? (bf16*)((char*)d_ws + 41943040) : nullptr;

  CvtSegs segs;
  int n = 0;
  segs.src[n] = X;   segs.dst[n] = Xb;            segs.cnt[n] = 16777216; n++;
  segs.src[n] = q_w; segs.dst[n] = wq_b;          segs.cnt[n] = 4194304;  n++;
  segs.src[n] = k_w; segs.dst[n] = wkv_b;         segs.cnt[n] = 262144;   n++;
  segs.src[n] = v_w; segs.dst[n] = wkv_b + 262144; segs.cnt[n] = 262144;  n++;
  segs.src[n] = q_b; segs.dst[n] = qb_b;          segs.cnt[n] = 2048;     n++;
  segs.src[n] = k_b; segs.dst[n] = kvb_b;         segs.cnt[n] = 128;      n++;
  segs.src[n] = v_b; segs.dst[n] = kvb_b + 128;   segs.cnt[n] = 128;      n++;
  if (big_ws) {
    segs.src[n] = o_w; segs.dst[n] = wo_b;        segs.cnt[n] = 4194304;  n++;
    segs.src[n] = o_b; segs.dst[n] = ob_b;        segs.cnt[n] = 2048;     n++;
  }
  segs.n = n;

  dim3 blk(256);
  cvt_kernel<<<dim3(1024), blk, 0, stream>>>(segs);
  // fused Q+KV projection: W = [wq_b; wkv_b] 2304x2048, bias = [qb_b; kvb_b]
  gemm_bt<<<dim3(64, 18), blk, 0, stream>>>(Xb, wq_b, qb_b, Qg, Kg, Vtg,
                                            8192, 2304, 2048, 0, 0, 4);
  mqa_attn<<<dim3(8, 64), blk, 0, stream>>>(Qg, Kg, Vtg, AO);
  if (big_ws)
    gemm_bt<<<dim3(64, 16), blk, 0, stream>>>(AO, wo_b, ob_b, d_out, nullptr, nullptr,
                                              8192, 2048, 2048, 0, 0, 2);
  else
    gemm_bt<<<dim3(64, 16), blk, 0, stream>>>(AO, o_w, o_b, d_out, nullptr, nullptr,
                                              8192, 2048, 2048, 1, 1, 2);
}